// Round 1
// baseline (3623.164 us; speedup 1.0000x reference)
//
#include <hip/hip_runtime.h>

// DeltanetHead: T=4096, B=8, C=1024, F=128
// Pipeline:
//   1. cvt x (fp32->bf16), pack 6 weight mats (+1/sqrt(F) fold into B_w) -> Wall bf16, bias fp32
//   2. bf16 MFMA GEMM: P[32768][768] = x @ Wall^T + bias, sigmoid on cols [512,640) (the I slot)
//      slots: 0=a 1=b(pre-scaled 1/sqrt(F)) 2=c 3=d 4=g(sigmoid(i)) 5=sel
//   3. scan kernel: rows split 2/wave over 512 waves; DPP wave-reduce for st@a; out via
//      global fp32 atomics into o32 (pre-zeroed); writes final state to d_out tail.
//   4. cvt o32->bf16, bf16 MFMA GEMM: y = o @ O_w^T  (fp32 out, d_out head)

#define T_DIM 4096
#define B_DIM 8
#define C_DIM 1024
#define F_DIM 128

typedef __attribute__((ext_vector_type(8))) short bf16x8;
typedef __attribute__((ext_vector_type(4))) float f32x4;

__device__ __forceinline__ unsigned short f2bf(float f) {
  unsigned u = __float_as_uint(f);
  u += 0x7fffu + ((u >> 16) & 1u);   // round-to-nearest-even
  return (unsigned short)(u >> 16);
}

// ---------------- elementwise fp32 -> bf16 convert (vectorized x4) ----------------
__global__ void cvt_kernel(const float* __restrict__ in, unsigned short* __restrict__ out, int n4) {
  int i = blockIdx.x * blockDim.x + threadIdx.x;
  int stride = gridDim.x * blockDim.x;
  for (; i < n4; i += stride) {
    float4 v = ((const float4*)in)[i];
    ushort4 r;
    r.x = f2bf(v.x); r.y = f2bf(v.y); r.z = f2bf(v.z); r.w = f2bf(v.w);
    ((ushort4*)out)[i] = r;
  }
}

// ---------------- pack 6 [F][C] weights -> Wall[768][1024] bf16 + bias[768] ----------------
__global__ void pack_w_kernel(const float* __restrict__ Aw, const float* __restrict__ Ab,
                              const float* __restrict__ Bw, const float* __restrict__ Bb,
                              const float* __restrict__ Cw, const float* __restrict__ Cb,
                              const float* __restrict__ Dw, const float* __restrict__ Db,
                              const float* __restrict__ Iw, const float* __restrict__ Ib,
                              const float* __restrict__ Sw, const float* __restrict__ Sb,
                              unsigned short* __restrict__ Wall, float* __restrict__ biasAll) {
  const float scaleB = 0.08838834764831845f;  // 1/sqrt(128), folded into b-projection
  int idx = blockIdx.x * 256 + threadIdx.x;
  if (idx < 768 * 1024) {
    int row = idx >> 10, c = idx & 1023;
    int slot = row >> 7, rr = row & 127;
    const float* W = slot == 0 ? Aw : slot == 1 ? Bw : slot == 2 ? Cw
                   : slot == 3 ? Dw : slot == 4 ? Iw : Sw;
    float v = W[rr * 1024 + c];
    if (slot == 1) v *= scaleB;
    Wall[idx] = f2bf(v);
  }
  if (idx < 768) {
    int slot = idx >> 7, rr = idx & 127;
    const float* Bv = slot == 0 ? Ab : slot == 1 ? Bb : slot == 2 ? Cb
                    : slot == 3 ? Db : slot == 4 ? Ib : Sb;
    float v = Bv[rr];
    if (slot == 1) v *= scaleB;
    biasAll[idx] = v;
  }
}

// ---------------- bf16 MFMA GEMM: C[M][N] = A[M][K] * B[N][K]^T (+bias, +sigmoid range) ----------------
// 128x128 tile, BK=32, 256 threads (4 waves, each a 64x64 quadrant of 4x4 16x16 MFMAs).
__global__ __launch_bounds__(256) void gemm_bt(
    const unsigned short* __restrict__ A,
    const unsigned short* __restrict__ Bm,
    float* __restrict__ Cm,
    const float* __restrict__ bias,
    int M, int N, int K, int sig_lo, int sig_hi) {
  __shared__ unsigned short As[128 * 32];
  __shared__ unsigned short Bs[128 * 32];
  const int tid = threadIdx.x;
  const int m0 = blockIdx.x * 128;
  const int n0 = blockIdx.y * 128;
  const int wv = tid >> 6, ln = tid & 63;
  const int mo = (wv & 1) * 64, no = (wv >> 1) * 64;
  const int lrow = ln & 15, lq = ln >> 4;
  f32x4 acc[4][4] = {};

  for (int kt = 0; kt < K; kt += 32) {
#pragma unroll
    for (int it = 0; it < 2; ++it) {
      int idx = it * 256 + tid;
      int row = idx >> 2, kc = idx & 3;
      *(int4*)&As[row * 32 + kc * 8] = *(const int4*)&A[(size_t)(m0 + row) * K + kt + kc * 8];
      *(int4*)&Bs[row * 32 + kc * 8] = *(const int4*)&Bm[(size_t)(n0 + row) * K + kt + kc * 8];
    }
    __syncthreads();
    bf16x8 af[4], bf[4];
#pragma unroll
    for (int i = 0; i < 4; ++i) {
      af[i] = *(const bf16x8*)&As[(mo + i * 16 + lrow) * 32 + lq * 8];
      bf[i] = *(const bf16x8*)&Bs[(no + i * 16 + lrow) * 32 + lq * 8];
    }
#pragma unroll
    for (int i = 0; i < 4; ++i)
#pragma unroll
      for (int j = 0; j < 4; ++j)
        acc[i][j] = __builtin_amdgcn_mfma_f32_16x16x32_bf16(af[i], bf[j], acc[i][j], 0, 0, 0);
    __syncthreads();
  }

#pragma unroll
  for (int i = 0; i < 4; ++i) {
#pragma unroll
    for (int j = 0; j < 4; ++j) {
      int col = n0 + no + j * 16 + lrow;
      float bv = bias ? bias[col] : 0.0f;
      bool sig = (col >= sig_lo) && (col < sig_hi);
#pragma unroll
      for (int r = 0; r < 4; ++r) {
        int row = m0 + mo + i * 16 + lq * 4 + r;
        float v = acc[i][j][r] + bv;
        if (sig) v = 1.0f / (1.0f + __expf(-v));
        Cm[(size_t)row * N + col] = v;
      }
    }
  }
}

// ---------------- wave-wide sum via DPP (result broadcast via readlane 63) ----------------
__device__ __forceinline__ float wave_sum64(float x) {
  x += __int_as_float(__builtin_amdgcn_update_dpp(0, __float_as_int(x), 0x111, 0xf, 0xf, false)); // row_shr:1
  x += __int_as_float(__builtin_amdgcn_update_dpp(0, __float_as_int(x), 0x112, 0xf, 0xf, false)); // row_shr:2
  x += __int_as_float(__builtin_amdgcn_update_dpp(0, __float_as_int(x), 0x114, 0xf, 0xf, false)); // row_shr:4
  x += __int_as_float(__builtin_amdgcn_update_dpp(0, __float_as_int(x), 0x118, 0xf, 0xf, false)); // row_shr:8
  x += __int_as_float(__builtin_amdgcn_update_dpp(0, __float_as_int(x), 0x142, 0xf, 0xf, false)); // row_bcast:15
  x += __int_as_float(__builtin_amdgcn_update_dpp(0, __float_as_int(x), 0x143, 0xf, 0xf, false)); // row_bcast:31
  return __int_as_float(__builtin_amdgcn_readlane(__float_as_int(x), 63));
}

// ---------------- sequential scan: grid (B=8, 16 groups) x 256 thr (4 waves, 2 rows/wave) ----------------
__global__ __launch_bounds__(256) void scan_kernel(
    const float* __restrict__ P,          // [T][B][6][128]
    const float* __restrict__ state_in,   // [B][128][128]
    float* __restrict__ o32,              // [T][B][128], pre-zeroed (atomic accumulate)
    float* __restrict__ state_out) {      // [B][128][128]
  const int b = blockIdx.x;
  const int g = blockIdx.y;
  const int wave = threadIdx.x >> 6;
  const int lane = threadIdx.x & 63;
  const int r0 = g * 8 + wave * 2;   // this wave's two rows
  const int j0 = lane * 2;           // this lane's two columns

  float2 st0 = *(const float2*)&state_in[((size_t)b * F_DIM + r0) * F_DIM + j0];
  float2 st1 = *(const float2*)&state_in[((size_t)b * F_DIM + r0 + 1) * F_DIM + j0];

  // preload t=0 step inputs
  const float* Pt = P + (size_t)b * 768;
  float2 a2 = *(const float2*)(Pt + 0 + j0);
  float2 b2 = *(const float2*)(Pt + 128 + j0);
  float2 d2 = *(const float2*)(Pt + 384 + j0);
  float2 g2 = *(const float2*)(Pt + 512 + j0);
  float c0 = Pt[256 + r0], c1 = Pt[256 + r0 + 1];
  float s0 = Pt[640 + r0], s1 = Pt[640 + r0 + 1];

  for (int t = 0; t < T_DIM; ++t) {
    // prefetch t+1 (off the serial chain; hides L1/L2 latency)
    int tn = (t + 1 < T_DIM) ? (t + 1) : (T_DIM - 1);
    const float* Pn = P + ((size_t)tn * B_DIM + b) * 768;
    float2 na = *(const float2*)(Pn + 0 + j0);
    float2 nb = *(const float2*)(Pn + 128 + j0);
    float2 nd = *(const float2*)(Pn + 384 + j0);
    float2 ng = *(const float2*)(Pn + 512 + j0);
    float nc0 = Pn[256 + r0], nc1 = Pn[256 + r0 + 1];
    float ns0 = Pn[640 + r0], ns1 = Pn[640 + r0 + 1];

    // v[i] = st[i,:] . a   (old state)
    float p0 = st0.x * a2.x + st0.y * a2.y;
    float p1 = st1.x * a2.x + st1.y * a2.y;
    float v0 = wave_sum64(p0);
    float v1 = wave_sum64(p1);

    // st[i,j] = st*g + v*b' + c*d   (b' already scaled by 1/sqrt(F))
    st0.x = st0.x * g2.x + v0 * b2.x + c0 * d2.x;
    st0.y = st0.y * g2.y + v0 * b2.y + c0 * d2.y;
    st1.x = st1.x * g2.x + v1 * b2.x + c1 * d2.x;
    st1.y = st1.y * g2.y + v1 * b2.y + c1 * d2.y;

    // out[j] += sel[i] * st_new[i,j]  (partial over this wave's 2 rows)
    float ox = s0 * st0.x + s1 * st1.x;
    float oy = s0 * st0.y + s1 * st1.y;
    float* od = o32 + ((size_t)t * B_DIM + b) * F_DIM + j0;
    unsafeAtomicAdd(od, ox);
    unsafeAtomicAdd(od + 1, oy);

    a2 = na; b2 = nb; d2 = nd; g2 = ng;
    c0 = nc0; c1 = nc1; s0 = ns0; s1 = ns1;
  }

  float* so = state_out + ((size_t)b * F_DIM + r0) * F_DIM + j0;
  *(float2*)so = st0;
  *(float2*)(so + F_DIM) = st1;
}

extern "C" void kernel_launch(void* const* d_in, const int* in_sizes, int n_in,
                              void* d_out, int out_size, void* d_ws, size_t ws_size,
                              hipStream_t stream) {
  const float* x  = (const float*)d_in[0];
  const float* st = (const float*)d_in[1];
  const float* Aw = (const float*)d_in[2];
  const float* Ab = (const float*)d_in[3];
  const float* Bw = (const float*)d_in[4];
  const float* Bb = (const float*)d_in[5];
  const float* Cw = (const float*)d_in[6];
  const float* Cb = (const float*)d_in[7];
  const float* Dw = (const float*)d_in[8];
  const float* Db = (const float*)d_in[9];
  const float* Iw = (const float*)d_in[10];
  const float* Ib = (const float*)d_in[11];
  const float* Sw = (const float*)d_in[12];
  const float* Sb = (const float*)d_in[13];
  const float* Ow = (const float*)d_in[14];

  float* y = (float*)d_out;                               // [T][B][C]
  float* state_out = y + (size_t)T_DIM * B_DIM * C_DIM;   // [B][F][F]

  // workspace carve (total ~186 MB)
  char* ws = (char*)d_ws;
  unsigned short* xb   = (unsigned short*)(ws);                 // 67,108,864 B : x bf16
  unsigned short* Wall = (unsigned short*)(ws + 67108864);      //  1,572,864 B : packed W bf16
  float* biasAll       = (float*)(ws + 68681728);               //      3,072 B
  unsigned short* Owb  = (unsigned short*)(ws + 68684800);      //    262,144 B : O_w bf16
  float* P             = (float*)(ws + 68946944);               // 100,663,296 B : projections
  float* o32           = (float*)(ws + 169610240);              // 16,777,216 B : scan out (atomics)
  unsigned short* ob   = (unsigned short*)(ws + 186387456);     //  8,388,608 B : o bf16

  hipMemsetAsync(o32, 0, 16777216, stream);
  cvt_kernel<<<4096, 256, 0, stream>>>(x, xb, 33554432 / 4);
  pack_w_kernel<<<3072, 256, 0, stream>>>(Aw, Ab, Bw, Bb, Cw, Cb, Dw, Db, Iw, Ib, Sw, Sb,
                                          Wall, biasAll);
  cvt_kernel<<<128, 256, 0, stream>>>(Ow, Owb, 131072 / 4);
  // projections: P = x @ Wall^T + bias, sigmoid on I-slot cols [512,640)
  gemm_bt<<<dim3(256, 6), 256, 0, stream>>>(xb, Wall, P, biasAll, 32768, 768, 1024, 512, 640);
  scan_kernel<<<dim3(8, 16), 256, 0, stream>>>(P, st, o32, state_out);
  cvt_kernel<<<4096, 256, 0, stream>>>(o32, ob, 4194304 / 4);
  // y = o @ O_w^T
  gemm_bt<<<dim3(256, 8), 256, 0, stream>>>(ob, Owb, y, nullptr, 32768, 1024, 128, 0, 0);
}

// Round 2
// 1605.057 us; speedup vs baseline: 2.2573x; 2.2573x over previous
//
#include <hip/hip_runtime.h>

// DeltanetHead: T=4096, B=8, C=1024, F=128
// R2: scan atomics removed. Per-block LDS reduce (1 barrier / 4 steps) -> bf16
// partials [G][T][B][128] -> small reduce kernel -> ob. G picked from ws_size.

#define T_DIM 4096
#define B_DIM 8
#define C_DIM 1024
#define F_DIM 128

typedef __attribute__((ext_vector_type(8))) short bf16x8;
typedef __attribute__((ext_vector_type(4))) float f32x4;

__device__ __forceinline__ unsigned short f2bf(float f) {
  unsigned u = __float_as_uint(f);
  u += 0x7fffu + ((u >> 16) & 1u);   // round-to-nearest-even
  return (unsigned short)(u >> 16);
}
__device__ __forceinline__ float bfu2f(unsigned u) { return __uint_as_float(u << 16); }

// ---------------- elementwise fp32 -> bf16 convert (vectorized x4) ----------------
__global__ void cvt_kernel(const float* __restrict__ in, unsigned short* __restrict__ out, int n4) {
  int i = blockIdx.x * blockDim.x + threadIdx.x;
  int stride = gridDim.x * blockDim.x;
  for (; i < n4; i += stride) {
    float4 v = ((const float4*)in)[i];
    ushort4 r;
    r.x = f2bf(v.x); r.y = f2bf(v.y); r.z = f2bf(v.z); r.w = f2bf(v.w);
    ((ushort4*)out)[i] = r;
  }
}

// ---------------- pack 6 [F][C] weights -> Wall[768][1024] bf16 + bias[768] ----------------
__global__ void pack_w_kernel(const float* __restrict__ Aw, const float* __restrict__ Ab,
                              const float* __restrict__ Bw, const float* __restrict__ Bb,
                              const float* __restrict__ Cw, const float* __restrict__ Cb,
                              const float* __restrict__ Dw, const float* __restrict__ Db,
                              const float* __restrict__ Iw, const float* __restrict__ Ib,
                              const float* __restrict__ Sw, const float* __restrict__ Sb,
                              unsigned short* __restrict__ Wall, float* __restrict__ biasAll) {
  const float scaleB = 0.08838834764831845f;  // 1/sqrt(128), folded into b-projection
  int idx = blockIdx.x * 256 + threadIdx.x;
  if (idx < 768 * 1024) {
    int row = idx >> 10, c = idx & 1023;
    int slot = row >> 7, rr = row & 127;
    const float* W = slot == 0 ? Aw : slot == 1 ? Bw : slot == 2 ? Cw
                   : slot == 3 ? Dw : slot == 4 ? Iw : Sw;
    float v = W[rr * 1024 + c];
    if (slot == 1) v *= scaleB;
    Wall[idx] = f2bf(v);
  }
  if (idx < 768) {
    int slot = idx >> 7, rr = idx & 127;
    const float* Bv = slot == 0 ? Ab : slot == 1 ? Bb : slot == 2 ? Cb
                    : slot == 3 ? Db : slot == 4 ? Ib : Sb;
    float v = Bv[rr];
    if (slot == 1) v *= scaleB;
    biasAll[idx] = v;
  }
}

// ---------------- bf16 MFMA GEMM: C[M][N] = A[M][K] * B[N][K]^T (+bias, +sigmoid range) ----------------
__global__ __launch_bounds__(256) void gemm_bt(
    const unsigned short* __restrict__ A,
    const unsigned short* __restrict__ Bm,
    float* __restrict__ Cm,
    const float* __restrict__ bias,
    int M, int N, int K, int sig_lo, int sig_hi) {
  __shared__ unsigned short As[128 * 32];
  __shared__ unsigned short Bs[128 * 32];
  const int tid = threadIdx.x;
  const int m0 = blockIdx.x * 128;
  const int n0 = blockIdx.y * 128;
  const int wv = tid >> 6, ln = tid & 63;
  const int mo = (wv & 1) * 64, no = (wv >> 1) * 64;
  const int lrow = ln & 15, lq = ln >> 4;
  f32x4 acc[4][4] = {};

  for (int kt = 0; kt < K; kt += 32) {
#pragma unroll
    for (int it = 0; it < 2; ++it) {
      int idx = it * 256 + tid;
      int row = idx >> 2, kc = idx & 3;
      *(int4*)&As[row * 32 + kc * 8] = *(const int4*)&A[(size_t)(m0 + row) * K + kt + kc * 8];
      *(int4*)&Bs[row * 32 + kc * 8] = *(const int4*)&Bm[(size_t)(n0 + row) * K + kt + kc * 8];
    }
    __syncthreads();
    bf16x8 af[4], bf[4];
#pragma unroll
    for (int i = 0; i < 4; ++i) {
      af[i] = *(const bf16x8*)&As[(mo + i * 16 + lrow) * 32 + lq * 8];
      bf[i] = *(const bf16x8*)&Bs[(no + i * 16 + lrow) * 32 + lq * 8];
    }
#pragma unroll
    for (int i = 0; i < 4; ++i)
#pragma unroll
      for (int j = 0; j < 4; ++j)
        acc[i][j] = __builtin_amdgcn_mfma_f32_16x16x32_bf16(af[i], bf[j], acc[i][j], 0, 0, 0);
    __syncthreads();
  }

#pragma unroll
  for (int i = 0; i < 4; ++i) {
#pragma unroll
    for (int j = 0; j < 4; ++j) {
      int col = n0 + no + j * 16 + lrow;
      float bv = bias ? bias[col] : 0.0f;
      bool sig = (col >= sig_lo) && (col < sig_hi);
#pragma unroll
      for (int r = 0; r < 4; ++r) {
        int row = m0 + mo + i * 16 + lq * 4 + r;
        float v = acc[i][j][r] + bv;
        if (sig) v = 1.0f / (1.0f + __expf(-v));
        Cm[(size_t)row * N + col] = v;
      }
    }
  }
}

// ---------------- wave-wide sum via DPP ----------------
__device__ __forceinline__ float wave_sum64(float x) {
  x += __int_as_float(__builtin_amdgcn_update_dpp(0, __float_as_int(x), 0x111, 0xf, 0xf, false)); // row_shr:1
  x += __int_as_float(__builtin_amdgcn_update_dpp(0, __float_as_int(x), 0x112, 0xf, 0xf, false)); // row_shr:2
  x += __int_as_float(__builtin_amdgcn_update_dpp(0, __float_as_int(x), 0x114, 0xf, 0xf, false)); // row_shr:4
  x += __int_as_float(__builtin_amdgcn_update_dpp(0, __float_as_int(x), 0x118, 0xf, 0xf, false)); // row_shr:8
  x += __int_as_float(__builtin_amdgcn_update_dpp(0, __float_as_int(x), 0x142, 0xf, 0xf, false)); // row_bcast:15
  x += __int_as_float(__builtin_amdgcn_update_dpp(0, __float_as_int(x), 0x143, 0xf, 0xf, false)); // row_bcast:31
  return __int_as_float(__builtin_amdgcn_readlane(__float_as_int(x), 63));
}

// ---------------- sequential scan ----------------
// grid (B, G), 256 thr (4 waves). Wave owns ROWS rows, lane owns 2 cols.
// Block partial out (16/8 rows) reduced in LDS once per 4 steps -> bf16 partial.
template <int ROWS>
__global__ __launch_bounds__(256) void scan_kernel(
    const float* __restrict__ P,          // [T][B][6][128] fp32
    const float* __restrict__ state_in,   // [B][128][128]
    unsigned short* __restrict__ o_part,  // [G][T][B][128] bf16
    float* __restrict__ state_out) {      // [B][128][128]
  const int b = blockIdx.x;
  const int gq = blockIdx.y;
  const int wave = threadIdx.x >> 6;
  const int lane = threadIdx.x & 63;
  const int r0 = gq * (4 * ROWS) + wave * ROWS;
  const int j0 = lane * 2;
  __shared__ float buf[2][4][4][128];   // [parity][wave][step-in-batch][col]

  float2 st[ROWS];
#pragma unroll
  for (int r = 0; r < ROWS; ++r)
    st[r] = *(const float2*)&state_in[((size_t)b * F_DIM + r0 + r) * F_DIM + j0];

  // preload t=0 step inputs
  const float* P0 = P + (size_t)b * 768;
  float2 a2 = *(const float2*)(P0 + 0 + j0);
  float2 b2 = *(const float2*)(P0 + 128 + j0);
  float2 d2 = *(const float2*)(P0 + 384 + j0);
  float2 g2 = *(const float2*)(P0 + 512 + j0);
  float cc[ROWS], ss[ROWS];
  if constexpr (ROWS == 2) {
    float2 v = *(const float2*)(P0 + 256 + r0); cc[0] = v.x; cc[1] = v.y;
    float2 w = *(const float2*)(P0 + 640 + r0); ss[0] = w.x; ss[1] = w.y;
  } else {
    float4 v = *(const float4*)(P0 + 256 + r0); cc[0] = v.x; cc[1] = v.y; cc[2] = v.z; cc[3] = v.w;
    float4 w = *(const float4*)(P0 + 640 + r0); ss[0] = w.x; ss[1] = w.y; ss[2] = w.z; ss[3] = w.w;
  }

  for (int t4 = 0; t4 < T_DIM; t4 += 4) {
    const int pb = (t4 >> 2) & 1;
#pragma unroll
    for (int k = 0; k < 4; ++k) {
      const int t = t4 + k;
      const int tn = (t + 1 < T_DIM) ? (t + 1) : (T_DIM - 1);
      const float* Pn = P + ((size_t)tn * B_DIM + b) * 768;
      float2 na = *(const float2*)(Pn + 0 + j0);
      float2 nb = *(const float2*)(Pn + 128 + j0);
      float2 nd = *(const float2*)(Pn + 384 + j0);
      float2 ng = *(const float2*)(Pn + 512 + j0);
      float nc[ROWS], ns[ROWS];
      if constexpr (ROWS == 2) {
        float2 v = *(const float2*)(Pn + 256 + r0); nc[0] = v.x; nc[1] = v.y;
        float2 w = *(const float2*)(Pn + 640 + r0); ns[0] = w.x; ns[1] = w.y;
      } else {
        float4 v = *(const float4*)(Pn + 256 + r0); nc[0] = v.x; nc[1] = v.y; nc[2] = v.z; nc[3] = v.w;
        float4 w = *(const float4*)(Pn + 640 + r0); ns[0] = w.x; ns[1] = w.y; ns[2] = w.z; ns[3] = w.w;
      }

      // v[r] = st[r,:] . a  (old state, wave-wide reduce over 128 cols)
      float vr[ROWS];
#pragma unroll
      for (int r = 0; r < ROWS; ++r)
        vr[r] = wave_sum64(st[r].x * a2.x + st[r].y * a2.y);

      // st update + partial out over this wave's rows
      float ox = 0.0f, oy = 0.0f;
#pragma unroll
      for (int r = 0; r < ROWS; ++r) {
        st[r].x = st[r].x * g2.x + vr[r] * b2.x + cc[r] * d2.x;
        st[r].y = st[r].y * g2.y + vr[r] * b2.y + cc[r] * d2.y;
        ox += ss[r] * st[r].x;
        oy += ss[r] * st[r].y;
      }
      *(float2*)&buf[pb][wave][k][j0] = make_float2(ox, oy);

      a2 = na; b2 = nb; d2 = nd; g2 = ng;
#pragma unroll
      for (int r = 0; r < ROWS; ++r) { cc[r] = nc[r]; ss[r] = ns[r]; }
    }
    __syncthreads();
    // cross-wave reduce of the 4-step batch: 256 thr x 2 items = 4 steps x 128 cols
#pragma unroll
    for (int h = 0; h < 2; ++h) {
      int it = threadIdx.x + h * 256;
      int k = it >> 7, col = it & 127;
      float s = buf[pb][0][k][col] + buf[pb][1][k][col] +
                buf[pb][2][k][col] + buf[pb][3][k][col];
      o_part[(((size_t)gq * T_DIM + t4 + k) * B_DIM + b) * F_DIM + col] = f2bf(s);
    }
    // no second barrier: parity double-buffer + the next batch's barrier orders reuse
  }

#pragma unroll
  for (int r = 0; r < ROWS; ++r)
    *(float2*)&state_out[((size_t)b * F_DIM + r0 + r) * F_DIM + j0] = st[r];
}

// ---------------- sum G bf16 partials -> ob bf16 (memory-bound) ----------------
__global__ void reduce_kernel(const unsigned short* __restrict__ o_part,
                              unsigned short* __restrict__ ob, int G) {
  const size_t NEL = (size_t)T_DIM * B_DIM * F_DIM;  // 4,194,304
  size_t i = ((size_t)blockIdx.x * 256 + threadIdx.x) * 8;
  if (i >= NEL) return;
  float acc[8] = {0, 0, 0, 0, 0, 0, 0, 0};
  for (int g = 0; g < G; ++g) {
    int4 v = *(const int4*)(o_part + (size_t)g * NEL + i);
    unsigned w0 = (unsigned)v.x, w1 = (unsigned)v.y, w2 = (unsigned)v.z, w3 = (unsigned)v.w;
    acc[0] += bfu2f(w0 & 0xffffu); acc[1] += bfu2f(w0 >> 16);
    acc[2] += bfu2f(w1 & 0xffffu); acc[3] += bfu2f(w1 >> 16);
    acc[4] += bfu2f(w2 & 0xffffu); acc[5] += bfu2f(w2 >> 16);
    acc[6] += bfu2f(w3 & 0xffffu); acc[7] += bfu2f(w3 >> 16);
  }
  int4 o;
  o.x = (int)((unsigned)f2bf(acc[0]) | ((unsigned)f2bf(acc[1]) << 16));
  o.y = (int)((unsigned)f2bf(acc[2]) | ((unsigned)f2bf(acc[3]) << 16));
  o.z = (int)((unsigned)f2bf(acc[4]) | ((unsigned)f2bf(acc[5]) << 16));
  o.w = (int)((unsigned)f2bf(acc[6]) | ((unsigned)f2bf(acc[7]) << 16));
  *(int4*)(ob + i) = o;
}

extern "C" void kernel_launch(void* const* d_in, const int* in_sizes, int n_in,
                              void* d_out, int out_size, void* d_ws, size_t ws_size,
                              hipStream_t stream) {
  const float* x  = (const float*)d_in[0];
  const float* st = (const float*)d_in[1];
  const float* Aw = (const float*)d_in[2];
  const float* Ab = (const float*)d_in[3];
  const float* Bw = (const float*)d_in[4];
  const float* Bb = (const float*)d_in[5];
  const float* Cw = (const float*)d_in[6];
  const float* Cb = (const float*)d_in[7];
  const float* Dw = (const float*)d_in[8];
  const float* Db = (const float*)d_in[9];
  const float* Iw = (const float*)d_in[10];
  const float* Ib = (const float*)d_in[11];
  const float* Sw = (const float*)d_in[12];
  const float* Sb = (const float*)d_in[13];
  const float* Ow = (const float*)d_in[14];

  float* y = (float*)d_out;                               // [T][B][C]
  float* state_out = y + (size_t)T_DIM * B_DIM * C_DIM;   // [B][F][F]

  // workspace carve:
  //   Wall      @ 0           (1,572,864)
  //   biasAll   @ 1,572,864   (3,072, padded)
  //   Owb       @ 1,576,960   (262,144)
  //   P         @ 1,839,104   (100,663,296)
  //   ob        @ 102,502,400 (8,388,608)
  //   xb        @ 110,891,008 (67,108,864)  -- dead after proj GEMM
  //   o_part    @ 110,891,008 (G * 8,388,608) reuses xb region; G=16 extends past it
  char* ws = (char*)d_ws;
  unsigned short* Wall = (unsigned short*)(ws);
  float* biasAll       = (float*)(ws + 1572864);
  unsigned short* Owb  = (unsigned short*)(ws + 1576960);
  float* P             = (float*)(ws + 1839104);
  unsigned short* ob   = (unsigned short*)(ws + 102502400);
  unsigned short* xb   = (unsigned short*)(ws + 110891008);
  unsigned short* o_part = xb;

  // G=16 wants 110,891,008 + 16*8,388,608 = 245,108,736 bytes of ws
  const int G = (ws_size >= 245108736u) ? 16 : 8;

  cvt_kernel<<<4096, 256, 0, stream>>>(x, xb, 33554432 / 4);
  pack_w_kernel<<<3072, 256, 0, stream>>>(Aw, Ab, Bw, Bb, Cw, Cb, Dw, Db, Iw, Ib, Sw, Sb,
                                          Wall, biasAll);
  cvt_kernel<<<128, 256, 0, stream>>>(Ow, Owb, 131072 / 4);
  // projections: P = x @ Wall^T + bias, sigmoid on I-slot cols [512,640)
  gemm_bt<<<dim3(256, 6), 256, 0, stream>>>(xb, Wall, P, biasAll, 32768, 768, 1024, 512, 640);
  if (G == 16)
    scan_kernel<2><<<dim3(8, 16), 256, 0, stream>>>(P, st, o_part, state_out);
  else
    scan_kernel<4><<<dim3(8, 8), 256, 0, stream>>>(P, st, o_part, state_out);
  reduce_kernel<<<2048, 256, 0, stream>>>(o_part, ob, G);
  // y = o @ O_w^T
  gemm_bt<<<dim3(256, 8), 256, 0, stream>>>(ob, Owb, y, nullptr, 32768, 1024, 128, 0, 0);
}

// Round 3
// 1245.426 us; speedup vs baseline: 2.9092x; 1.2888x over previous
//
#include <hip/hip_runtime.h>

// DeltanetHead: T=4096, B=8, C=1024, F=128
// R3: scan latency fix — 4-step register-ring prefetch of the P stream
// (distance-4 covers L2/L3 latency; round 2 had distance-1 and stalled
// ~600 cyc/step), barrier batched to 8 steps (32 KB LDS, parity dbuf).

#define T_DIM 4096
#define B_DIM 8
#define C_DIM 1024
#define F_DIM 128

typedef __attribute__((ext_vector_type(8))) short bf16x8;
typedef __attribute__((ext_vector_type(4))) float f32x4;

__device__ __forceinline__ unsigned short f2bf(float f) {
  unsigned u = __float_as_uint(f);
  u += 0x7fffu + ((u >> 16) & 1u);   // round-to-nearest-even
  return (unsigned short)(u >> 16);
}
__device__ __forceinline__ float bfu2f(unsigned u) { return __uint_as_float(u << 16); }

// ---------------- elementwise fp32 -> bf16 convert (vectorized x4) ----------------
__global__ void cvt_kernel(const float* __restrict__ in, unsigned short* __restrict__ out, int n4) {
  int i = blockIdx.x * blockDim.x + threadIdx.x;
  int stride = gridDim.x * blockDim.x;
  for (; i < n4; i += stride) {
    float4 v = ((const float4*)in)[i];
    ushort4 r;
    r.x = f2bf(v.x); r.y = f2bf(v.y); r.z = f2bf(v.z); r.w = f2bf(v.w);
    ((ushort4*)out)[i] = r;
  }
}

// ---------------- pack 6 [F][C] weights -> Wall[768][1024] bf16 + bias[768] ----------------
__global__ void pack_w_kernel(const float* __restrict__ Aw, const float* __restrict__ Ab,
                              const float* __restrict__ Bw, const float* __restrict__ Bb,
                              const float* __restrict__ Cw, const float* __restrict__ Cb,
                              const float* __restrict__ Dw, const float* __restrict__ Db,
                              const float* __restrict__ Iw, const float* __restrict__ Ib,
                              const float* __restrict__ Sw, const float* __restrict__ Sb,
                              unsigned short* __restrict__ Wall, float* __restrict__ biasAll) {
  const float scaleB = 0.08838834764831845f;  // 1/sqrt(128), folded into b-projection
  int idx = blockIdx.x * 256 + threadIdx.x;
  if (idx < 768 * 1024) {
    int row = idx >> 10, c = idx & 1023;
    int slot = row >> 7, rr = row & 127;
    const float* W = slot == 0 ? Aw : slot == 1 ? Bw : slot == 2 ? Cw
                   : slot == 3 ? Dw : slot == 4 ? Iw : Sw;
    float v = W[rr * 1024 + c];
    if (slot == 1) v *= scaleB;
    Wall[idx] = f2bf(v);
  }
  if (idx < 768) {
    int slot = idx >> 7, rr = idx & 127;
    const float* Bv = slot == 0 ? Ab : slot == 1 ? Bb : slot == 2 ? Cb
                    : slot == 3 ? Db : slot == 4 ? Ib : Sb;
    float v = Bv[rr];
    if (slot == 1) v *= scaleB;
    biasAll[idx] = v;
  }
}

// ---------------- bf16 MFMA GEMM: C[M][N] = A[M][K] * B[N][K]^T (+bias, +sigmoid range) ----------------
__global__ __launch_bounds__(256) void gemm_bt(
    const unsigned short* __restrict__ A,
    const unsigned short* __restrict__ Bm,
    float* __restrict__ Cm,
    const float* __restrict__ bias,
    int M, int N, int K, int sig_lo, int sig_hi) {
  __shared__ unsigned short As[128 * 32];
  __shared__ unsigned short Bs[128 * 32];
  const int tid = threadIdx.x;
  const int m0 = blockIdx.x * 128;
  const int n0 = blockIdx.y * 128;
  const int wv = tid >> 6, ln = tid & 63;
  const int mo = (wv & 1) * 64, no = (wv >> 1) * 64;
  const int lrow = ln & 15, lq = ln >> 4;
  f32x4 acc[4][4] = {};

  for (int kt = 0; kt < K; kt += 32) {
#pragma unroll
    for (int it = 0; it < 2; ++it) {
      int idx = it * 256 + tid;
      int row = idx >> 2, kc = idx & 3;
      *(int4*)&As[row * 32 + kc * 8] = *(const int4*)&A[(size_t)(m0 + row) * K + kt + kc * 8];
      *(int4*)&Bs[row * 32 + kc * 8] = *(const int4*)&Bm[(size_t)(n0 + row) * K + kt + kc * 8];
    }
    __syncthreads();
    bf16x8 af[4], bf[4];
#pragma unroll
    for (int i = 0; i < 4; ++i) {
      af[i] = *(const bf16x8*)&As[(mo + i * 16 + lrow) * 32 + lq * 8];
      bf[i] = *(const bf16x8*)&Bs[(no + i * 16 + lrow) * 32 + lq * 8];
    }
#pragma unroll
    for (int i = 0; i < 4; ++i)
#pragma unroll
      for (int j = 0; j < 4; ++j)
        acc[i][j] = __builtin_amdgcn_mfma_f32_16x16x32_bf16(af[i], bf[j], acc[i][j], 0, 0, 0);
    __syncthreads();
  }

#pragma unroll
  for (int i = 0; i < 4; ++i) {
#pragma unroll
    for (int j = 0; j < 4; ++j) {
      int col = n0 + no + j * 16 + lrow;
      float bv = bias ? bias[col] : 0.0f;
      bool sig = (col >= sig_lo) && (col < sig_hi);
#pragma unroll
      for (int r = 0; r < 4; ++r) {
        int row = m0 + mo + i * 16 + lq * 4 + r;
        float v = acc[i][j][r] + bv;
        if (sig) v = 1.0f / (1.0f + __expf(-v));
        Cm[(size_t)row * N + col] = v;
      }
    }
  }
}

// ---------------- wave-wide sum via DPP ----------------
__device__ __forceinline__ float wave_sum64(float x) {
  x += __int_as_float(__builtin_amdgcn_update_dpp(0, __float_as_int(x), 0x111, 0xf, 0xf, false)); // row_shr:1
  x += __int_as_float(__builtin_amdgcn_update_dpp(0, __float_as_int(x), 0x112, 0xf, 0xf, false)); // row_shr:2
  x += __int_as_float(__builtin_amdgcn_update_dpp(0, __float_as_int(x), 0x114, 0xf, 0xf, false)); // row_shr:4
  x += __int_as_float(__builtin_amdgcn_update_dpp(0, __float_as_int(x), 0x118, 0xf, 0xf, false)); // row_shr:8
  x += __int_as_float(__builtin_amdgcn_update_dpp(0, __float_as_int(x), 0x142, 0xf, 0xf, false)); // row_bcast:15
  x += __int_as_float(__builtin_amdgcn_update_dpp(0, __float_as_int(x), 0x143, 0xf, 0xf, false)); // row_bcast:31
  return __int_as_float(__builtin_amdgcn_readlane(__float_as_int(x), 63));
}

// ---------------- sequential scan ----------------
// grid (B, G), 256 thr (4 waves). Wave owns ROWS rows, lane owns 2 cols.
// 4-slot register ring prefetches P 4 steps ahead; LDS cross-wave reduce
// once per 8 steps (parity double-buffered, single barrier per batch).
template <int ROWS>
__global__ __launch_bounds__(256) void scan_kernel(
    const float* __restrict__ P,          // [T][B][6][128] fp32
    const float* __restrict__ state_in,   // [B][128][128]
    unsigned short* __restrict__ o_part,  // [G][T][B][128] bf16
    float* __restrict__ state_out) {      // [B][128][128]
  const int b = blockIdx.x;
  const int gq = blockIdx.y;
  const int wave = threadIdx.x >> 6;
  const int lane = threadIdx.x & 63;
  const int r0 = gq * (4 * ROWS) + wave * ROWS;
  const int j0 = lane * 2;
  __shared__ float buf[2][4][8][128];   // [parity][wave][step-in-batch][col] = 32 KB

  float2 st[ROWS];
#pragma unroll
  for (int r = 0; r < ROWS; ++r)
    st[r] = *(const float2*)&state_in[((size_t)b * F_DIM + r0 + r) * F_DIM + j0];

  // 4-slot prefetch ring
  float2 Pa[4], Pb[4], Pd[4], Pg[4];
  float Pc[4][ROWS], Ps[4][ROWS];
#pragma unroll
  for (int k = 0; k < 4; ++k) {
    const float* Pt = P + ((size_t)k * B_DIM + b) * 768;
    Pa[k] = *(const float2*)(Pt + 0 + j0);
    Pb[k] = *(const float2*)(Pt + 128 + j0);
    Pd[k] = *(const float2*)(Pt + 384 + j0);
    Pg[k] = *(const float2*)(Pt + 512 + j0);
    if constexpr (ROWS == 2) {
      float2 v = *(const float2*)(Pt + 256 + r0); Pc[k][0] = v.x; Pc[k][1] = v.y;
      float2 w = *(const float2*)(Pt + 640 + r0); Ps[k][0] = w.x; Ps[k][1] = w.y;
    } else {
      float4 v = *(const float4*)(Pt + 256 + r0);
      Pc[k][0] = v.x; Pc[k][1] = v.y; Pc[k][2] = v.z; Pc[k][3] = v.w;
      float4 w = *(const float4*)(Pt + 640 + r0);
      Ps[k][0] = w.x; Ps[k][1] = w.y; Ps[k][2] = w.z; Ps[k][3] = w.w;
    }
  }

  for (int t8 = 0; t8 < T_DIM; t8 += 8) {
    const int pb = (t8 >> 3) & 1;
#pragma unroll
    for (int k = 0; k < 8; ++k) {
      const int sl = k & 3;
      // grab current step's values (SSA copies; regalloc coalesces)
      float2 a2 = Pa[sl], b2 = Pb[sl], d2 = Pd[sl], g2 = Pg[sl];
      float cc[ROWS], ss[ROWS];
#pragma unroll
      for (int r = 0; r < ROWS; ++r) { cc[r] = Pc[sl][r]; ss[r] = Ps[sl][r]; }

      // issue prefetch for step t+4 into this slot (distance-4, off the chain)
      int tl = t8 + k + 4; tl = tl < T_DIM ? tl : T_DIM - 1;
      const float* Pn = P + ((size_t)tl * B_DIM + b) * 768;
      Pa[sl] = *(const float2*)(Pn + 0 + j0);
      Pb[sl] = *(const float2*)(Pn + 128 + j0);
      Pd[sl] = *(const float2*)(Pn + 384 + j0);
      Pg[sl] = *(const float2*)(Pn + 512 + j0);
      if constexpr (ROWS == 2) {
        float2 v = *(const float2*)(Pn + 256 + r0); Pc[sl][0] = v.x; Pc[sl][1] = v.y;
        float2 w = *(const float2*)(Pn + 640 + r0); Ps[sl][0] = w.x; Ps[sl][1] = w.y;
      } else {
        float4 v = *(const float4*)(Pn + 256 + r0);
        Pc[sl][0] = v.x; Pc[sl][1] = v.y; Pc[sl][2] = v.z; Pc[sl][3] = v.w;
        float4 w = *(const float4*)(Pn + 640 + r0);
        Ps[sl][0] = w.x; Ps[sl][1] = w.y; Ps[sl][2] = w.z; Ps[sl][3] = w.w;
      }

      // v[r] = st[r,:] . a  (old state, wave-wide reduce over 128 cols)
      float vr[ROWS];
#pragma unroll
      for (int r = 0; r < ROWS; ++r)
        vr[r] = wave_sum64(st[r].x * a2.x + st[r].y * a2.y);

      // st update + partial out over this wave's rows
      float ox = 0.0f, oy = 0.0f;
#pragma unroll
      for (int r = 0; r < ROWS; ++r) {
        st[r].x = st[r].x * g2.x + vr[r] * b2.x + cc[r] * d2.x;
        st[r].y = st[r].y * g2.y + vr[r] * b2.y + cc[r] * d2.y;
        ox += ss[r] * st[r].x;
        oy += ss[r] * st[r].y;
      }
      *(float2*)&buf[pb][wave][k][j0] = make_float2(ox, oy);
    }
    __syncthreads();
    // cross-wave reduce of the 8-step batch: 256 thr x 4 items = 8 steps x 128 cols
#pragma unroll
    for (int h = 0; h < 4; ++h) {
      int it = threadIdx.x + h * 256;
      int k = it >> 7, col = it & 127;
      float s = buf[pb][0][k][col] + buf[pb][1][k][col] +
                buf[pb][2][k][col] + buf[pb][3][k][col];
      o_part[(((size_t)gq * T_DIM + t8 + k) * B_DIM + b) * F_DIM + col] = f2bf(s);
    }
    // no second barrier: parity double-buffer + the next batch's barrier orders reuse
  }

#pragma unroll
  for (int r = 0; r < ROWS; ++r)
    *(float2*)&state_out[((size_t)b * F_DIM + r0 + r) * F_DIM + j0] = st[r];
}

// ---------------- sum G bf16 partials -> ob bf16 (memory-bound) ----------------
__global__ void reduce_kernel(const unsigned short* __restrict__ o_part,
                              unsigned short* __restrict__ ob, int G) {
  const size_t NEL = (size_t)T_DIM * B_DIM * F_DIM;  // 4,194,304
  size_t i = ((size_t)blockIdx.x * 256 + threadIdx.x) * 8;
  if (i >= NEL) return;
  float acc[8] = {0, 0, 0, 0, 0, 0, 0, 0};
  for (int g = 0; g < G; ++g) {
    int4 v = *(const int4*)(o_part + (size_t)g * NEL + i);
    unsigned w0 = (unsigned)v.x, w1 = (unsigned)v.y, w2 = (unsigned)v.z, w3 = (unsigned)v.w;
    acc[0] += bfu2f(w0 & 0xffffu); acc[1] += bfu2f(w0 >> 16);
    acc[2] += bfu2f(w1 & 0xffffu); acc[3] += bfu2f(w1 >> 16);
    acc[4] += bfu2f(w2 & 0xffffu); acc[5] += bfu2f(w2 >> 16);
    acc[6] += bfu2f(w3 & 0xffffu); acc[7] += bfu2f(w3 >> 16);
  }
  int4 o;
  o.x = (int)((unsigned)f2bf(acc[0]) | ((unsigned)f2bf(acc[1]) << 16));
  o.y = (int)((unsigned)f2bf(acc[2]) | ((unsigned)f2bf(acc[3]) << 16));
  o.z = (int)((unsigned)f2bf(acc[4]) | ((unsigned)f2bf(acc[5]) << 16));
  o.w = (int)((unsigned)f2bf(acc[6]) | ((unsigned)f2bf(acc[7]) << 16));
  *(int4*)(ob + i) = o;
}

extern "C" void kernel_launch(void* const* d_in, const int* in_sizes, int n_in,
                              void* d_out, int out_size, void* d_ws, size_t ws_size,
                              hipStream_t stream) {
  const float* x  = (const float*)d_in[0];
  const float* st = (const float*)d_in[1];
  const float* Aw = (const float*)d_in[2];
  const float* Ab = (const float*)d_in[3];
  const float* Bw = (const float*)d_in[4];
  const float* Bb = (const float*)d_in[5];
  const float* Cw = (const float*)d_in[6];
  const float* Cb = (const float*)d_in[7];
  const float* Dw = (const float*)d_in[8];
  const float* Db = (const float*)d_in[9];
  const float* Iw = (const float*)d_in[10];
  const float* Ib = (const float*)d_in[11];
  const float* Sw = (const float*)d_in[12];
  const float* Sb = (const float*)d_in[13];
  const float* Ow = (const float*)d_in[14];

  float* y = (float*)d_out;                               // [T][B][C]
  float* state_out = y + (size_t)T_DIM * B_DIM * C_DIM;   // [B][F][F]

  // workspace carve:
  //   Wall      @ 0           (1,572,864)
  //   biasAll   @ 1,572,864   (3,072, padded)
  //   Owb       @ 1,576,960   (262,144)
  //   P         @ 1,839,104   (100,663,296)
  //   ob        @ 102,502,400 (8,388,608)
  //   xb        @ 110,891,008 (67,108,864)  -- dead after proj GEMM
  //   o_part    @ 110,891,008 (G * 8,388,608) reuses xb region; G=16 extends past it
  char* ws = (char*)d_ws;
  unsigned short* Wall = (unsigned short*)(ws);
  float* biasAll       = (float*)(ws + 1572864);
  unsigned short* Owb  = (unsigned short*)(ws + 1576960);
  float* P             = (float*)(ws + 1839104);
  unsigned short* ob   = (unsigned short*)(ws + 102502400);
  unsigned short* xb   = (unsigned short*)(ws + 110891008);
  unsigned short* o_part = xb;

  // G=16 wants 110,891,008 + 16*8,388,608 = 245,108,736 bytes of ws
  const int G = (ws_size >= 245108736u) ? 16 : 8;

  cvt_kernel<<<4096, 256, 0, stream>>>(x, xb, 33554432 / 4);
  pack_w_kernel<<<3072, 256, 0, stream>>>(Aw, Ab, Bw, Bb, Cw, Cb, Dw, Db, Iw, Ib, Sw, Sb,
                                          Wall, biasAll);
  cvt_kernel<<<128, 256, 0, stream>>>(Ow, Owb, 131072 / 4);
  // projections: P = x @ Wall^T + bias, sigmoid on I-slot cols [512,640)
  gemm_bt<<<dim3(256, 6), 256, 0, stream>>>(xb, Wall, P, biasAll, 32768, 768, 1024, 512, 640);
  if (G == 16)
    scan_kernel<2><<<dim3(8, 16), 256, 0, stream>>>(P, st, o_part, state_out);
  else
    scan_kernel<4><<<dim3(8, 8), 256, 0, stream>>>(P, st, o_part, state_out);
  reduce_kernel<<<2048, 256, 0, stream>>>(o_part, ob, G);
  // y = o @ O_w^T
  gemm_bt<<<dim3(256, 8), 256, 0, stream>>>(ob, Owb, y, nullptr, 32768, 1024, 128, 0, 0);
}